// Round 1
// baseline (75.930 us; speedup 1.0000x reference)
//
#include <hip/hip_runtime.h>

// APLoss: reference reduces analytically to per-row sums.
//   s_all[i] = sum_j relu(1 - f_i + y_j)^2
//   s_pos[i] = sum_{j: y_true[j]==1} relu(1 - f_i + y_j)^2
//   ua = 0.01*u_all[idx] + 0.99*s_all/N ; up = 0.01*u_pos[idx] + 0.99*s_pos/N
//   row[i] = (up*s_all - ua*s_pos)/ua^2 ; loss = sum_i row[i] / (N_POS*N)
// fp64 reductions: exact cancellation in (up*s_all - ua*s_pos) amplifies
// rounding ~25-50x; fp64 keeps us ~1e-6 vs the 1.5e-4 (2%) threshold.

constexpr int BLOCK = 256;

__global__ __launch_bounds__(BLOCK) void aploss_rows(
    const float* __restrict__ y_pred,
    const float* __restrict__ y_true,
    const float* __restrict__ u_all,
    const float* __restrict__ u_pos,
    const int*   __restrict__ index_s,
    double*      __restrict__ row_out,
    int n)
{
    const int i   = blockIdx.x;          // row = positive sample index
    const int tid = threadIdx.x;
    const float f_i = y_pred[i];         // f_ps[i] == y_pred[i] for i < n_pos

    const float4* yp4 = (const float4*)y_pred;
    const float4* yt4 = (const float4*)y_true;
    const int n4 = n >> 2;               // n = 16384 -> 4096 float4 groups

    double s_all = 0.0, s_pos = 0.0;
    for (int j = tid; j < n4; j += BLOCK) {
        float4 yp = yp4[j];
        float4 yt = yt4[j];
        float sa = 0.f, sp = 0.f;
        float d, s;
        d = 1.0f - (f_i - yp.x); d = fmaxf(d, 0.f); s = d * d; sa += s; sp += (yt.x == 1.0f) ? s : 0.f;
        d = 1.0f - (f_i - yp.y); d = fmaxf(d, 0.f); s = d * d; sa += s; sp += (yt.y == 1.0f) ? s : 0.f;
        d = 1.0f - (f_i - yp.z); d = fmaxf(d, 0.f); s = d * d; sa += s; sp += (yt.z == 1.0f) ? s : 0.f;
        d = 1.0f - (f_i - yp.w); d = fmaxf(d, 0.f); s = d * d; sa += s; sp += (yt.w == 1.0f) ? s : 0.f;
        s_all += (double)sa;
        s_pos += (double)sp;
    }

    // wave-64 butterfly reduce (double = two 32-bit shuffles each)
    #pragma unroll
    for (int off = 32; off > 0; off >>= 1) {
        s_all += __shfl_down(s_all, off, 64);
        s_pos += __shfl_down(s_pos, off, 64);
    }

    __shared__ double sh_all[BLOCK / 64];
    __shared__ double sh_pos[BLOCK / 64];
    const int wave = tid >> 6;
    const int lane = tid & 63;
    if (lane == 0) { sh_all[wave] = s_all; sh_pos[wave] = s_pos; }
    __syncthreads();

    if (tid == 0) {
        double ta = sh_all[0] + sh_all[1] + sh_all[2] + sh_all[3];
        double tp = sh_pos[0] + sh_pos[1] + sh_pos[2] + sh_pos[3];
        const int idx = index_s[i];      // index_ps[i]
        const double inv_n = 1.0 / (double)n;
        const double ua = 0.01 * (double)u_all[idx] + 0.99 * (ta * inv_n);
        const double up = 0.01 * (double)u_pos[idx] + 0.99 * (tp * inv_n);
        row_out[i] = (up * ta - ua * tp) / (ua * ua);
    }
}

__global__ __launch_bounds__(BLOCK) void aploss_reduce(
    const double* __restrict__ row_terms,
    float* __restrict__ out,
    int n_pos, int n)
{
    const int tid = threadIdx.x;
    double s = 0.0;
    for (int i = tid; i < n_pos; i += BLOCK) s += row_terms[i];
    #pragma unroll
    for (int off = 32; off > 0; off >>= 1) s += __shfl_down(s, off, 64);

    __shared__ double sh[BLOCK / 64];
    const int wave = tid >> 6;
    const int lane = tid & 63;
    if (lane == 0) sh[wave] = s;
    __syncthreads();
    if (tid == 0) {
        double tot = sh[0] + sh[1] + sh[2] + sh[3];
        out[0] = (float)(tot / ((double)n_pos * (double)n));
    }
}

extern "C" void kernel_launch(void* const* d_in, const int* in_sizes, int n_in,
                              void* d_out, int out_size, void* d_ws, size_t ws_size,
                              hipStream_t stream) {
    const float* y_pred  = (const float*)d_in[0];
    const float* y_true  = (const float*)d_in[1];
    const float* u_all   = (const float*)d_in[2];
    const float* u_pos   = (const float*)d_in[3];
    const int*   index_s = (const int*)d_in[4];
    // d_in[5] is n_pos as a 1-elem device array; grid dims must be host-side,
    // and the problem fixes n_pos = 2048 (y_true layout in setup_inputs).
    const int n     = in_sizes[0];   // 16384
    const int n_pos = 2048;

    double* row_terms = (double*)d_ws;   // 2048 * 8B = 16 KiB scratch
    float*  out       = (float*)d_out;

    aploss_rows<<<n_pos, BLOCK, 0, stream>>>(y_pred, y_true, u_all, u_pos,
                                             index_s, row_terms, n);
    aploss_reduce<<<1, BLOCK, 0, stream>>>(row_terms, out, n_pos, n);
}

// Round 2
// 71.899 us; speedup vs baseline: 1.0561x; 1.0561x over previous
//
#include <hip/hip_runtime.h>

// APLoss reduced analytically (no O(N_POS*N) matrix materialization):
//   s_all[i] = sum_j relu(1 - f_i + y_j)^2
//   s_pos[i] = sum_j relu(1 - f_i + y_j)^2 * y_true[j]   (y_true in {0,1})
//   ua = 0.01*u_all[idx] + 0.99*s_all/N ; up = 0.01*u_pos[idx] + 0.99*s_pos/N
//   row[i] = (up*s_all - ua*s_pos)/ua^2 ; loss = sum_i row[i] / (N_POS*N)
//
// R1 post-mortem: 1-row/block streamed 268 MB through L2; row-blocking 8x
// cuts traffic to 33 MB and makes VALU (~2 us aggregate) the floor.
// fp32 per-thread accumulators (32 cells/row), fp64 cross-wave + epilogue:
// the (up*s_all - ua*s_pos) cancellation is exact in the 0.99-terms, so
// fp64 there keeps absmax ~1e-6 vs the 1.5e-4 threshold (R1: absmax 0.0).

constexpr int ROWS    = 8;    // rows per block
constexpr int THREADS = 512;  // 8 waves, 2 per SIMD

__global__ __launch_bounds__(THREADS) void aploss_rows(
    const float* __restrict__ y_pred,
    const float* __restrict__ y_true,
    const float* __restrict__ u_all,
    const float* __restrict__ u_pos,
    const int*   __restrict__ index_s,
    double*      __restrict__ row_out,
    int n)
{
    const int i0  = blockIdx.x * ROWS;
    const int tid = threadIdx.x;

    float f[ROWS];
    #pragma unroll
    for (int r = 0; r < ROWS; ++r) f[r] = y_pred[i0 + r];  // block-uniform

    const float4* yp4 = (const float4*)y_pred;
    const float4* yt4 = (const float4*)y_true;
    const int n4 = n >> 2;  // 4096 float4 groups

    float sa[ROWS], sp[ROWS];
    #pragma unroll
    for (int r = 0; r < ROWS; ++r) { sa[r] = 0.f; sp[r] = 0.f; }

    for (int j = tid; j < n4; j += THREADS) {   // 8 groups/thread
        const float4 yp = yp4[j];
        const float4 yt = yt4[j];
        const float c0 = 1.0f + yp.x, c1 = 1.0f + yp.y;
        const float c2 = 1.0f + yp.z, c3 = 1.0f + yp.w;
        #pragma unroll
        for (int r = 0; r < ROWS; ++r) {
            float m, t;
            m = fmaxf(c0 - f[r], 0.f); sa[r] = fmaf(m, m, sa[r]); t = m * yt.x; sp[r] = fmaf(t, m, sp[r]);
            m = fmaxf(c1 - f[r], 0.f); sa[r] = fmaf(m, m, sa[r]); t = m * yt.y; sp[r] = fmaf(t, m, sp[r]);
            m = fmaxf(c2 - f[r], 0.f); sa[r] = fmaf(m, m, sa[r]); t = m * yt.z; sp[r] = fmaf(t, m, sp[r]);
            m = fmaxf(c3 - f[r], 0.f); sa[r] = fmaf(m, m, sa[r]); t = m * yt.w; sp[r] = fmaf(t, m, sp[r]);
        }
    }

    // wave-64 butterfly reduce (fp32 partials: ~5500 magnitude, rel err ~1e-6)
    #pragma unroll
    for (int off = 32; off > 0; off >>= 1) {
        #pragma unroll
        for (int r = 0; r < ROWS; ++r) {
            sa[r] += __shfl_down(sa[r], off, 64);
            sp[r] += __shfl_down(sp[r], off, 64);
        }
    }

    __shared__ float sh_a[THREADS / 64][ROWS];
    __shared__ float sh_p[THREADS / 64][ROWS];
    const int wave = tid >> 6;
    const int lane = tid & 63;
    if (lane == 0) {
        #pragma unroll
        for (int r = 0; r < ROWS; ++r) { sh_a[wave][r] = sa[r]; sh_p[wave][r] = sp[r]; }
    }
    __syncthreads();

    if (tid < ROWS) {  // thread r finalizes row i0+r in fp64
        double ta = 0.0, tp = 0.0;
        #pragma unroll
        for (int w = 0; w < THREADS / 64; ++w) {
            ta += (double)sh_a[w][tid];
            tp += (double)sh_p[w][tid];
        }
        const int idx = index_s[i0 + tid];
        const double inv_n = 1.0 / (double)n;
        const double ua = 0.01 * (double)u_all[idx] + 0.99 * (ta * inv_n);
        const double up = 0.01 * (double)u_pos[idx] + 0.99 * (tp * inv_n);
        row_out[i0 + tid] = (up * ta - ua * tp) / (ua * ua);
    }
}

__global__ __launch_bounds__(256) void aploss_reduce(
    const double* __restrict__ row_terms,
    float* __restrict__ out,
    int n_pos, int n)
{
    const int tid = threadIdx.x;
    double s = 0.0;
    for (int i = tid; i < n_pos; i += 256) s += row_terms[i];
    #pragma unroll
    for (int off = 32; off > 0; off >>= 1) s += __shfl_down(s, off, 64);

    __shared__ double sh[4];
    const int wave = tid >> 6;
    const int lane = tid & 63;
    if (lane == 0) sh[wave] = s;
    __syncthreads();
    if (tid == 0) {
        double tot = sh[0] + sh[1] + sh[2] + sh[3];
        out[0] = (float)(tot / ((double)n_pos * (double)n));
    }
}

extern "C" void kernel_launch(void* const* d_in, const int* in_sizes, int n_in,
                              void* d_out, int out_size, void* d_ws, size_t ws_size,
                              hipStream_t stream) {
    const float* y_pred  = (const float*)d_in[0];
    const float* y_true  = (const float*)d_in[1];
    const float* u_all   = (const float*)d_in[2];
    const float* u_pos   = (const float*)d_in[3];
    const int*   index_s = (const int*)d_in[4];
    const int n     = in_sizes[0];   // 16384
    const int n_pos = 2048;          // fixed by problem (grid dim is host-side)

    double* row_terms = (double*)d_ws;   // 16 KiB scratch
    float*  out       = (float*)d_out;

    aploss_rows<<<n_pos / ROWS, THREADS, 0, stream>>>(
        y_pred, y_true, u_all, u_pos, index_s, row_terms, n);
    aploss_reduce<<<1, 256, 0, stream>>>(row_terms, out, n_pos, n);
}